// Round 6
// baseline (295.709 us; speedup 1.0000x reference)
//
#include <hip/hip_runtime.h>

typedef _Float16 f16;
typedef f16 f16x2 __attribute__((ext_vector_type(2)));
typedef f16 f16x4 __attribute__((ext_vector_type(4)));
typedef f16 f16x8 __attribute__((ext_vector_type(8)));
typedef float f32x16 __attribute__((ext_vector_type(16)));
typedef unsigned int u32;

#define MFMA32(a, b, c) __builtin_amdgcn_mfma_f32_32x32x16_f16((a), (b), (c), 0, 0, 0)

namespace {
constexpr int SN = 2048;   // sequence length
constexpr int DN = 128;    // head dim
constexpr int KVB = 64;    // kv tile rows
constexpr int NT = SN / KVB;         // 32 kv tiles
constexpr int QB = 256;    // q rows per block = 8 waves x 32
// (1/sqrt(128)) * log2(e): softmax in exp2 domain
constexpr float SCALE_L2E = 0.1275213897f;
constexpr float THR = 8.0f;          // defer-max threshold (exp2 domain, P <= 2^8)
}

// XOR swizzles (f16-element units; byte-swizzle = <<4)
__device__ __forceinline__ int kidx(int kv, int d) { return kv * DN + (d ^ ((kv & 7) << 3)); }
__device__ __forceinline__ int vidx(int d, int kv) { return d * KVB + (kv ^ (((d ^ (d >> 3)) & 7) << 3)); }

// 64 KB LDS/block, 512 threads = 8 waves (2/SIMD), 1 block/CU.
__global__ __launch_bounds__(512, 2)
void mca_kernel(const float* __restrict__ x1, const float* __restrict__ x2,
                float* __restrict__ out)
{
    __shared__ __align__(16) f16 sK[2][KVB * DN];   // [kv][d]  2 x 16 KB
    __shared__ __align__(16) f16 sV[2][DN * KVB];   // [d][kv]  2 x 16 KB (V==K data, transposed)

    // XCD-chunked swizzle: XCD k gets 32 consecutive works (one pass, 4 batches).
    const int gid  = blockIdx.x;
    const int work = (gid & 7) * 32 + (gid >> 3);
    const int pass = work >> 7;
    const int b    = (work >> 3) & 15;
    const int q0   = (work & 7) << 8;            // * QB

    const int t  = threadIdx.x;
    const int w  = t >> 6;
    const int l  = t & 63;
    const int lq = l & 31;                       // q column owned by this lane
    const int hi = l >> 5;

    const int kvg = t >> 5;                      // staging: kv rows 4*kvg..+4
    const int dg  = t & 31;                      // staging: d cols 4*dg..+4

    const float* xq  = pass ? x2 : x1;
    const float* xkv = pass ? x1 : x2;
    const float* qp  = xq + ((size_t)b * SN + q0 + w * 32 + lq) * DN;
    const float* kb  = xkv + (size_t)b * SN * DN;

    // ---- Q B-fragments in registers (col=lq, k-elem j -> d=16c+8hi+j), pre-scaled ----
    f16x8 qf[8];
    #pragma unroll
    for (int c = 0; c < 8; ++c) {
        const float* p = qp + 16 * c + 8 * hi;
        float4 a0 = *(const float4*)p;
        float4 a1 = *(const float4*)(p + 4);
        f16x8 q;
        q[0] = (f16)(a0.x * SCALE_L2E); q[1] = (f16)(a0.y * SCALE_L2E);
        q[2] = (f16)(a0.z * SCALE_L2E); q[3] = (f16)(a0.w * SCALE_L2E);
        q[4] = (f16)(a1.x * SCALE_L2E); q[5] = (f16)(a1.y * SCALE_L2E);
        q[6] = (f16)(a1.z * SCALE_L2E); q[7] = (f16)(a1.w * SCALE_L2E);
        qf[c] = q;
    }

    // staging registers (issue-early / write-late)
    float hv[4][4];

    auto LOAD = [&](int tile) {
        const float* src = kb + ((size_t)tile * KVB + 4 * kvg) * DN + 4 * dg;
        #pragma unroll
        for (int rr = 0; rr < 4; ++rr) {
            float4 a = *(const float4*)(src + rr * DN);
            hv[rr][0] = a.x; hv[rr][1] = a.y; hv[rr][2] = a.z; hv[rr][3] = a.w;
        }
    };
    auto WRITE = [&](int buf) {
        #pragma unroll
        for (int rr = 0; rr < 4; ++rr) {          // sK rows
            f16x4 kp;
            #pragma unroll
            for (int j = 0; j < 4; ++j) kp[j] = (f16)hv[rr][j];
            *(f16x4*)&sK[buf][kidx(4 * kvg + rr, 4 * dg)] = kp;
        }
        #pragma unroll
        for (int i = 0; i < 4; ++i) {             // sV cols (transposed)
            f16x4 vp;
            #pragma unroll
            for (int rr = 0; rr < 4; ++rr) vp[rr] = (f16)hv[rr][i];
            *(f16x4*)&sV[buf][vidx(4 * dg + i, 4 * kvg)] = vp;
        }
    };

    f32x16 oAcc[4] = {{}, {}, {}, {}};           // O^T: d-rows x (q col = lq)
    float mrun = -1e30f;
    float lrun = 0.f;

    // ---- prologue: stage tile 0 ----
    LOAD(0);
    WRITE(0);
    __syncthreads();

    for (int tile = 0; tile < NT; ++tile) {
        const int cur = tile & 1;
        if (tile + 1 < NT) LOAD(tile + 1);       // issue early; hides under QK^T

        // ---- QK^T swapped: S^T[kv][q], lane owns column q=lq ----
        f32x16 sacc[2] = {{}, {}};
        __builtin_amdgcn_s_setprio(1);
        #pragma unroll
        for (int c = 0; c < 8; ++c) {
            f16x8 ka0 = *(const f16x8*)&sK[cur][kidx(lq,      16 * c + 8 * hi)];
            f16x8 ka1 = *(const f16x8*)&sK[cur][kidx(32 + lq, 16 * c + 8 * hi)];
            sacc[0] = MFMA32(ka0, qf[c], sacc[0]);
            sacc[1] = MFMA32(ka1, qf[c], sacc[1]);
        }
        __builtin_amdgcn_s_setprio(0);

        // ---- online softmax, fully in-register (rows split lane vs lane^32) ----
        float tm = sacc[0][0];
        #pragma unroll
        for (int kvb = 0; kvb < 2; ++kvb)
            #pragma unroll
            for (int r = 0; r < 16; ++r) tm = fmaxf(tm, sacc[kvb][r]);
        tm = fmaxf(tm, __shfl_xor(tm, 32));
        if (!__all(tm - mrun <= THR)) {          // defer-max (T13)
            float mnew = fmaxf(mrun, tm);
            float corr = exp2f(mrun - mnew);
            #pragma unroll
            for (int db = 0; db < 4; ++db) oAcc[db] *= corr;
            lrun *= corr;
            mrun = mnew;
        }
        float p[32];
        float ps = 0.f;
        #pragma unroll
        for (int kvb = 0; kvb < 2; ++kvb)
            #pragma unroll
            for (int r = 0; r < 16; ++r) {
                float pv = exp2f(sacc[kvb][r] - mrun);
                p[kvb * 16 + r] = pv;
                ps += pv;
            }
        ps += __shfl_xor(ps, 32);
        lrun += ps;

        // ---- P -> f16 B-fragments (P^T: col=q=lq, k=kv) via pack + lane^32 exchange ----
        // reg r of sacc[kvb] holds kv row 32*kvb + (r&3)+8*(r>>2)+4*hi.
        f16x8 pf[4];
        #pragma unroll
        for (int f = 0; f < 4; ++f) {
            const int base = (f >> 1) * 16 + (f & 1) * 8;
            u32 wd[4];
            #pragma unroll
            for (int W = 0; W < 2; ++W) {
                union { f16x2 h; u32 u; } A, B;
                A.h[0] = (f16)p[base + 2 * W];     A.h[1] = (f16)p[base + 2 * W + 1];
                B.h[0] = (f16)p[base + 2 * W + 4]; B.h[1] = (f16)p[base + 2 * W + 5];
                u32 xA = (u32)__shfl_xor((int)A.u, 32);
                u32 xB = (u32)__shfl_xor((int)B.u, 32);
                wd[W]     = hi ? xB : A.u;         // k-elems {2W, 2W+1}
                wd[W + 2] = hi ? B.u : xA;         // k-elems {2W+4, 2W+5}
            }
            union { u32 u[4]; f16x8 v; } asm_;
            asm_.u[0] = wd[0]; asm_.u[1] = wd[1]; asm_.u[2] = wd[2]; asm_.u[3] = wd[3];
            pf[f] = asm_.v;
        }

        // ---- write next tile into alternate buffers (vmcnt waits here) ----
        if (tile + 1 < NT) WRITE(cur ^ 1);

        // ---- PV: O^T[d][q] += V^T[d][kv] · P^T[kv][q] ----
        __builtin_amdgcn_s_setprio(1);
        #pragma unroll
        for (int db = 0; db < 4; ++db) {
            #pragma unroll
            for (int f = 0; f < 4; ++f) {
                f16x8 va = *(const f16x8*)&sV[cur][vidx(db * 32 + lq, f * 16 + 8 * hi)];
                oAcc[db] = MFMA32(va, pf[f], oAcc[db]);
            }
        }
        __builtin_amdgcn_s_setprio(0);

        __syncthreads();                          // one barrier per tile
    }

    // ---- finalize: O /= l (in-lane), combine passes via atomicAdd ----
    const float inv = 1.0f / lrun;
    float* ob = out + ((size_t)b * SN + q0 + w * 32 + lq) * DN;
    #pragma unroll
    for (int db = 0; db < 4; ++db)
        #pragma unroll
        for (int rr = 0; rr < 4; ++rr) {
            const int d0 = db * 32 + rr * 8 + hi * 4;   // reg 4*rr+i -> d = d0+i
            #pragma unroll
            for (int i = 0; i < 4; ++i)
                atomicAdd(&ob[d0 + i], oAcc[db][rr * 4 + i] * inv);
        }
}

extern "C" void kernel_launch(void* const* d_in, const int* in_sizes, int n_in,
                              void* d_out, int out_size, void* d_ws, size_t ws_size,
                              hipStream_t stream) {
    const float* x1 = (const float*)d_in[0];
    const float* x2 = (const float*)d_in[1];
    float* out = (float*)d_out;
    const int B = in_sizes[0] / (SN * DN);       // 16
    hipMemsetAsync(d_out, 0, (size_t)out_size * sizeof(float), stream);
    dim3 grid(2 * B * (SN / QB));                // 256 blocks = 1 per CU, one pass each
    dim3 block(512);
    hipLaunchKernelGGL(mca_kernel, grid, block, 0, stream, x1, x2, out);
}

// Round 7
// 132.380 us; speedup vs baseline: 2.2338x; 2.2338x over previous
//
#include <hip/hip_runtime.h>

typedef _Float16 f16;
typedef f16 f16x2 __attribute__((ext_vector_type(2)));
typedef f16 f16x4 __attribute__((ext_vector_type(4)));
typedef f16 f16x8 __attribute__((ext_vector_type(8)));
typedef float f32x16 __attribute__((ext_vector_type(16)));
typedef unsigned int u32;

#define MFMA32(a, b, c) __builtin_amdgcn_mfma_f32_32x32x16_f16((a), (b), (c), 0, 0, 0)

namespace {
constexpr int SN = 2048;   // sequence length
constexpr int DN = 128;    // head dim
constexpr int KVB = 64;    // kv tile rows
constexpr int NT = SN / KVB;         // 32 kv tiles
constexpr int QB = 128;    // q rows per block = 4 waves x 32
// (1/sqrt(128)) * log2(e): softmax in exp2 domain
constexpr float SCALE_L2E = 0.1275213897f;
constexpr float THR = 8.0f;          // defer-max threshold (exp2 domain)
}

// XOR swizzles (f16-element units)
__device__ __forceinline__ int kidx(int kv, int d) { return kv * DN + (d ^ ((kv & 7) << 3)); }
__device__ __forceinline__ int vidx(int d, int kv) { return d * KVB + (kv ^ (((d ^ (d >> 3)) & 7) << 3)); }

// 64 KB LDS/block, 256 threads = 4 waves; 2 blocks/CU = 8 waves/CU (2/SIMD).
__global__ __launch_bounds__(256, 2)
void mca_kernel(const float* __restrict__ x1, const float* __restrict__ x2,
                float* __restrict__ out)
{
    __shared__ __align__(16) f16 sK[2][KVB * DN];   // [kv][d]  2 x 16 KB
    __shared__ __align__(16) f16 sV[2][DN * KVB];   // [d][kv]  2 x 16 KB (V==K, transposed)

    // XCD-chunked swizzle: XCD k gets works [64k, 64k+64).
    const int gid  = blockIdx.x;
    const int work = (gid & 7) * 64 + (gid >> 3);
    const int pass = work >> 8;
    const int b    = (work >> 4) & 15;
    const int q0   = (work & 15) * QB;

    const int t  = threadIdx.x;
    const int w  = t >> 6;
    const int l  = t & 63;
    const int lq = l & 31;                       // q column owned by this lane
    const int hi = l >> 5;

    const int kvg = t >> 5;                      // staging: kv rows 8*kvg..+8
    const int dg  = t & 31;                      // staging: d cols 4*dg..+4

    const float* xq  = pass ? x2 : x1;
    const float* xkv = pass ? x1 : x2;
    const float* qp  = xq + ((size_t)b * SN + q0 + w * 32 + lq) * DN;
    const float* kb  = xkv + (size_t)b * SN * DN;

    // ---- Q B-fragments (col=lq, k-elem j -> d=16c+8hi+j), pre-scaled ----
    f16x8 qf[8];
    #pragma unroll
    for (int c = 0; c < 8; ++c) {
        const float* p = qp + 16 * c + 8 * hi;
        float4 a0 = *(const float4*)p;
        float4 a1 = *(const float4*)(p + 4);
        f16x8 q;
        q[0] = (f16)(a0.x * SCALE_L2E); q[1] = (f16)(a0.y * SCALE_L2E);
        q[2] = (f16)(a0.z * SCALE_L2E); q[3] = (f16)(a0.w * SCALE_L2E);
        q[4] = (f16)(a1.x * SCALE_L2E); q[5] = (f16)(a1.y * SCALE_L2E);
        q[6] = (f16)(a1.z * SCALE_L2E); q[7] = (f16)(a1.w * SCALE_L2E);
        qf[c] = q;
    }

    // staging registers (issue-early / write-late)
    float hv[8][4];

    auto LOAD = [&](int tile) {
        const float* src = kb + ((size_t)tile * KVB + 8 * kvg) * DN + 4 * dg;
        #pragma unroll
        for (int rr = 0; rr < 8; ++rr) {
            float4 a = *(const float4*)(src + rr * DN);
            hv[rr][0] = a.x; hv[rr][1] = a.y; hv[rr][2] = a.z; hv[rr][3] = a.w;
        }
    };
    auto WRITE = [&](int buf) {
        #pragma unroll
        for (int rr = 0; rr < 8; ++rr) {          // sK rows (b64, bank floor)
            f16x4 kp;
            #pragma unroll
            for (int j = 0; j < 4; ++j) kp[j] = (f16)hv[rr][j];
            *(f16x4*)&sK[buf][kidx(8 * kvg + rr, 4 * dg)] = kp;
        }
        #pragma unroll
        for (int i = 0; i < 4; ++i) {             // sV cols (b128; 8-run stays contiguous under vidx)
            f16x8 vp;
            #pragma unroll
            for (int rr = 0; rr < 8; ++rr) vp[rr] = (f16)hv[rr][i];
            *(f16x8*)&sV[buf][vidx(4 * dg + i, 8 * kvg)] = vp;
        }
    };

    f32x16 oAcc[4] = {{}, {}, {}, {}};           // O^T: d rows x (q col = lq)
    float mrun = -1e30f;
    float lrun = 0.f;

    LOAD(0);
    WRITE(0);
    __syncthreads();

    for (int tile = 0; tile < NT; ++tile) {
        const int cur = tile & 1;
        if (tile + 1 < NT) LOAD(tile + 1);       // issue early

        // ---- QK^T swapped: S^T[kv][q], lane owns column q=lq ----
        f32x16 sacc[2] = {{}, {}};
        __builtin_amdgcn_s_setprio(1);
        #pragma unroll
        for (int c = 0; c < 8; ++c) {
            f16x8 ka0 = *(const f16x8*)&sK[cur][kidx(lq,      16 * c + 8 * hi)];
            f16x8 ka1 = *(const f16x8*)&sK[cur][kidx(32 + lq, 16 * c + 8 * hi)];
            sacc[0] = MFMA32(ka0, qf[c], sacc[0]);
            sacc[1] = MFMA32(ka1, qf[c], sacc[1]);
        }
        __builtin_amdgcn_s_setprio(0);

        // ---- online softmax, in-register; tree reductions (depth 5) ----
        float mx[16];
        #pragma unroll
        for (int r = 0; r < 16; ++r) mx[r] = fmaxf(sacc[0][r], sacc[1][r]);
        #pragma unroll
        for (int s = 8; s >= 1; s >>= 1)
            #pragma unroll
            for (int r = 0; r < s; ++r) mx[r] = fmaxf(mx[r], mx[r + s]);
        float tm = fmaxf(mx[0], __shfl_xor(mx[0], 32));
        if (!__all(tm - mrun <= THR)) {          // defer-max (T13)
            float mnew = fmaxf(mrun, tm);
            float corr = exp2f(mrun - mnew);
            #pragma unroll
            for (int db = 0; db < 4; ++db) oAcc[db] *= corr;
            lrun *= corr;
            mrun = mnew;
        }
        float p[32];
        #pragma unroll
        for (int kvb = 0; kvb < 2; ++kvb)
            #pragma unroll
            for (int r = 0; r < 16; ++r)
                p[kvb * 16 + r] = exp2f(sacc[kvb][r] - mrun);
        float sm[16];
        #pragma unroll
        for (int r = 0; r < 16; ++r) sm[r] = p[r] + p[r + 16];
        #pragma unroll
        for (int s = 8; s >= 1; s >>= 1)
            #pragma unroll
            for (int r = 0; r < s; ++r) sm[r] += sm[r + s];
        lrun += sm[0] + __shfl_xor(sm[0], 32);

        // ---- P -> f16 B-fragments (col=q=lq, k=kv) via pack + lane^32 exchange ----
        // reg r of sacc[kvb] holds kv row 32*kvb + (r&3)+8*(r>>2)+4*hi.
        f16x8 pf[4];
        #pragma unroll
        for (int f = 0; f < 4; ++f) {
            const int base = (f >> 1) * 16 + (f & 1) * 8;
            u32 wd[4];
            #pragma unroll
            for (int W = 0; W < 2; ++W) {
                union { f16x2 h; u32 u; } A, B;
                A.h[0] = (f16)p[base + 2 * W];     A.h[1] = (f16)p[base + 2 * W + 1];
                B.h[0] = (f16)p[base + 2 * W + 4]; B.h[1] = (f16)p[base + 2 * W + 5];
                u32 xA = (u32)__shfl_xor((int)A.u, 32);
                u32 xB = (u32)__shfl_xor((int)B.u, 32);
                wd[W]     = hi ? xB : A.u;
                wd[W + 2] = hi ? B.u : xA;
            }
            union { u32 u[4]; f16x8 v; } cvt;
            cvt.u[0] = wd[0]; cvt.u[1] = wd[1]; cvt.u[2] = wd[2]; cvt.u[3] = wd[3];
            pf[f] = cvt.v;
        }

        if (tile + 1 < NT) WRITE(cur ^ 1);       // vmcnt waits here, covered by above

        // ---- PV: O^T[d][q] += V^T[d][kv] · P^T[kv][q] ----
        __builtin_amdgcn_s_setprio(1);
        #pragma unroll
        for (int db = 0; db < 4; ++db) {
            #pragma unroll
            for (int f = 0; f < 4; ++f) {
                f16x8 va = *(const f16x8*)&sV[cur][vidx(db * 32 + lq, f * 16 + 8 * hi)];
                oAcc[db] = MFMA32(va, pf[f], oAcc[db]);
            }
        }
        __builtin_amdgcn_s_setprio(0);

        __syncthreads();
    }

    // ---- epilogue: transpose O^T via per-wave LDS scratch, coalesced atomicAdd ----
    const float inv = 1.0f / lrun;
    float* sO = (w < 2) ? ((float*)sK) + w * (32 * 128)
                        : ((float*)sV) + (w - 2) * (32 * 128);
    #pragma unroll
    for (int db = 0; db < 4; ++db)
        #pragma unroll
        for (int rr = 0; rr < 4; ++rr) {
            const int d0 = db * 32 + rr * 8 + hi * 4;
            float4 st;
            st.x = oAcc[db][rr * 4 + 0] * inv;
            st.y = oAcc[db][rr * 4 + 1] * inv;
            st.z = oAcc[db][rr * 4 + 2] * inv;
            st.w = oAcc[db][rr * 4 + 3] * inv;
            // swizzle flips bits 2..4 of d: bank-floor on store and load
            *(float4*)&sO[lq * 128 + (d0 ^ ((lq & 7) << 2))] = st;
        }
    // wave-internal RAW on LDS: compiler inserts lgkmcnt; no barrier needed
    float* ob = out + ((size_t)b * SN + q0 + w * 32) * DN;
    #pragma unroll 4
    for (int q = 0; q < 32; ++q) {
        const int sw = (q & 7) << 2;
        float v0 = sO[q * 128 + (l ^ sw)];
        float v1 = sO[q * 128 + ((l + 64) ^ sw)];
        atomicAdd(&ob[q * DN + l], v0);
        atomicAdd(&ob[q * DN + 64 + l], v1);
    }
}

extern "C" void kernel_launch(void* const* d_in, const int* in_sizes, int n_in,
                              void* d_out, int out_size, void* d_ws, size_t ws_size,
                              hipStream_t stream) {
    const float* x1 = (const float*)d_in[0];
    const float* x2 = (const float*)d_in[1];
    float* out = (float*)d_out;
    const int B = in_sizes[0] / (SN * DN);       // 16
    hipMemsetAsync(d_out, 0, (size_t)out_size * sizeof(float), stream);
    dim3 grid(2 * B * (SN / QB));                // 512 blocks = 2 per CU, one pass each
    dim3 block(256);
    hipLaunchKernelGGL(mca_kernel, grid, block, 0, stream, x1, x2, out);
}